// Round 8
// baseline (49.891 us; speedup 1.0000x reference)
//
#include <hip/hip_runtime.h>
#include <hip/hip_bf16.h>

// TT embedding: vocab 65536, dim 1024, rank 16.
// out[v,d] = sum_{r1..r4} c0[0,i0,r1] c1[r1,i1,r2] c2[r2,i2,r3] c3[r3,i3,r4] c4[r4,i4,0]
//   i0=v>>11, i1=(v>>6)&31, i2=(v>>1)&31, i3=(v&1)*16+(d>>6), i4=d&63
//
// R7 lesson: all fused structures latency-starved (VALUBusy ~14%, occ ~20%,
// only ~1.5 blocks/CU live). R8: two-kernel split, BOTH barrier-free:
//  A: 16 tokens/block, stages 1-3 entirely within 16-lane groups (each group
//     inside one wave64 -> zero __syncthreads), w4 rows to ws planes,
//     coalesced float4 stores.
//  B: TB=4 tokens/block, 4096 blocks, no LDS, no barriers: w-rows straight
//     from ws (per-wave: 4 x 64B broadcast lines per plane), 2-deep register
//     pipeline, c4 slice in 64 VGPRs. Same summation orders as R5 (absmax 0).

#define TA 16   // tokens per block, kernel A
#define TB 4    // tokens per block, kernel B

#define STEP(WV, k)                              \
    acc.x = fmaf(WV, c4v[k].x, acc.x);           \
    acc.y = fmaf(WV, c4v[k].y, acc.y);           \
    acc.z = fmaf(WV, c4v[k].z, acc.z);           \
    acc.w = fmaf(WV, c4v[k].w, acc.w);

__global__ __launch_bounds__(256) void tt_stage123(
    const float* __restrict__ c0, const float* __restrict__ c1,
    const float* __restrict__ c2, const float* __restrict__ c3,
    const int*   __restrict__ idx, float* __restrict__ wsp, int n_tokens)
{
    const int t = threadIdx.x;
    const int base = blockIdx.x * TA;
    const int g = t >> 4, r = t & 15;
    const int token = base + g;
    const int v = (token < n_tokens) ? idx[token] : 0;

    // Each 16-lane group (one token) lives inside a single wave64:
    // no __syncthreads anywhere; compiler lgkmcnt orders the LDS RAWs.
    __shared__ float w2[TA][17];
    __shared__ float w3[TA][17];

    // Stage 1: w2[g][r] = sum_r1 c0[i0,r1] * c1[r1,i1,r]
    {
        const int i0 = (v >> 11) & 31;
        const int i1 = (v >> 6) & 31;
        float acc = 0.f;
        #pragma unroll
        for (int r1 = 0; r1 < 16; ++r1)
            acc = fmaf(c0[i0 * 16 + r1], c1[(r1 * 32 + i1) * 16 + r], acc);
        w2[g][r] = acc;
    }
    // Stage 2: w3[g][r] = sum_r2 w2[g][r2] * c2[r2,i2,r]   (same wave)
    {
        const int i2 = (v >> 1) & 31;
        float acc = 0.f;
        #pragma unroll
        for (int r2 = 0; r2 < 16; ++r2)
            acc = fmaf(w2[g][r2], c2[(r2 * 32 + i2) * 16 + r], acc);
        w3[g][r] = acc;
    }
    // Stage 3: w4row[d1=r][r4] = sum_r3 w3[g][r3] * c3[r3,i3,r4] -> ws planes
    {
        const int d1 = r;
        const int i3 = ((v & 1) << 4) + d1;
        float4 a0 = {0,0,0,0}, a1 = {0,0,0,0}, a2 = {0,0,0,0}, a3 = {0,0,0,0};
        #pragma unroll
        for (int r3 = 0; r3 < 16; ++r3) {
            const float wv = w3[g][r3];
            const float4* row = (const float4*)(c3 + (r3 * 32 + i3) * 16);
            float4 b0 = row[0], b1 = row[1], b2 = row[2], b3 = row[3];
            a0.x = fmaf(wv, b0.x, a0.x); a0.y = fmaf(wv, b0.y, a0.y);
            a0.z = fmaf(wv, b0.z, a0.z); a0.w = fmaf(wv, b0.w, a0.w);
            a1.x = fmaf(wv, b1.x, a1.x); a1.y = fmaf(wv, b1.y, a1.y);
            a1.z = fmaf(wv, b1.z, a1.z); a1.w = fmaf(wv, b1.w, a1.w);
            a2.x = fmaf(wv, b2.x, a2.x); a2.y = fmaf(wv, b2.y, a2.y);
            a2.z = fmaf(wv, b2.z, a2.z); a2.w = fmaf(wv, b2.w, a2.w);
            a3.x = fmaf(wv, b3.x, a3.x); a3.y = fmaf(wv, b3.y, a3.y);
            a3.z = fmaf(wv, b3.z, a3.z); a3.w = fmaf(wv, b3.w, a3.w);
        }
        if (token < n_tokens) {
            const int m = (base << 4) + t;         // token*16 + d1, lane-contiguous
            const int plane = n_tokens << 4;       // float4s per plane
            float4* p = (float4*)wsp;
            p[m]             = a0;                 // r4 0..3
            p[plane + m]     = a1;                 // r4 4..7
            p[2 * plane + m] = a2;                 // r4 8..11
            p[3 * plane + m] = a3;                 // r4 12..15
        }
    }
}

__global__ __launch_bounds__(256) void tt_stage4(
    const float* __restrict__ c4, const float* __restrict__ wsp,
    float* __restrict__ out, int n_tokens)
{
    const int t = threadIdx.x;
    const int base = blockIdx.x * TB;
    const int d1  = t >> 4;
    const int i4b = (t & 15) << 2;

    float4 c4v[16];                                // 64 VGPRs, reused over TB tokens
    #pragma unroll
    for (int r4 = 0; r4 < 16; ++r4)
        c4v[r4] = *(const float4*)(c4 + (r4 << 6) + i4b);

    const float4* p = (const float4*)wsp;
    const int plane = n_tokens << 4;

    // prime the 2-deep pipeline
    int m = (base << 4) + d1;
    float4 wa = p[m], wb = p[plane + m], wc = p[2 * plane + m], wd = p[3 * plane + m];

    float* outp = out + (size_t)base * 1024 + (t << 2);

    #pragma unroll
    for (int gg = 0; gg < TB; ++gg) {
        float4 na, nb, nc, nd;
        if (gg + 1 < TB) {                         // compile-time after unroll
            const int mn = m + 16;
            na = p[mn]; nb = p[plane + mn]; nc = p[2 * plane + mn]; nd = p[3 * plane + mn];
        }

        float4 acc = {0,0,0,0};
        STEP(wa.x,  0) STEP(wa.y,  1) STEP(wa.z,  2) STEP(wa.w,  3)
        STEP(wb.x,  4) STEP(wb.y,  5) STEP(wb.z,  6) STEP(wb.w,  7)
        STEP(wc.x,  8) STEP(wc.y,  9) STEP(wc.z, 10) STEP(wc.w, 11)
        STEP(wd.x, 12) STEP(wd.y, 13) STEP(wd.z, 14) STEP(wd.w, 15)

        if (base + gg < n_tokens)
            *(float4*)(outp + (size_t)gg * 1024) = acc;

        wa = na; wb = nb; wc = nc; wd = nd;
        m += 16;
    }
}

// ---------- Fallback: R6/R7 fused kernel (used only if ws too small) ----------
__global__ __launch_bounds__(256) void tt_embed_fused(
    const float* __restrict__ c0, const float* __restrict__ c1,
    const float* __restrict__ c2, const float* __restrict__ c3,
    const float* __restrict__ c4, const int* __restrict__ idx,
    float* __restrict__ out, int n_tokens)
{
    const int t = threadIdx.x;
    const int base = blockIdx.x * 8;
    __shared__ float w4[8][16][20];
    __shared__ float w2[8][17];
    __shared__ float w3[8][17];

    const int i4b = (t & 15) << 2;
    float4 c4v[16];
    #pragma unroll
    for (int r4 = 0; r4 < 16; ++r4)
        c4v[r4] = *(const float4*)(c4 + (r4 << 6) + i4b);

    if (t < 128) {
        const int g = t >> 4, r = t & 15;
        const int token = base + g;
        const int v = (token < n_tokens) ? idx[token] : 0;
        {
            const int i0 = (v >> 11) & 31, i1 = (v >> 6) & 31;
            float acc = 0.f;
            #pragma unroll
            for (int r1 = 0; r1 < 16; ++r1)
                acc = fmaf(c0[i0 * 16 + r1], c1[(r1 * 32 + i1) * 16 + r], acc);
            w2[g][r] = acc;
        }
        {
            const int i2 = (v >> 1) & 31;
            float acc = 0.f;
            #pragma unroll
            for (int r2 = 0; r2 < 16; ++r2)
                acc = fmaf(w2[g][r2], c2[(r2 * 32 + i2) * 16 + r], acc);
            w3[g][r] = acc;
        }
        {
            const int d1 = r;
            const int i3 = ((v & 1) << 4) + d1;
            float4 a0 = {0,0,0,0}, a1 = {0,0,0,0}, a2 = {0,0,0,0}, a3 = {0,0,0,0};
            #pragma unroll
            for (int r3 = 0; r3 < 16; ++r3) {
                const float wv = w3[g][r3];
                const float4* row = (const float4*)(c3 + (r3 * 32 + i3) * 16);
                float4 b0 = row[0], b1 = row[1], b2 = row[2], b3 = row[3];
                a0.x = fmaf(wv, b0.x, a0.x); a0.y = fmaf(wv, b0.y, a0.y);
                a0.z = fmaf(wv, b0.z, a0.z); a0.w = fmaf(wv, b0.w, a0.w);
                a1.x = fmaf(wv, b1.x, a1.x); a1.y = fmaf(wv, b1.y, a1.y);
                a1.z = fmaf(wv, b1.z, a1.z); a1.w = fmaf(wv, b1.w, a1.w);
                a2.x = fmaf(wv, b2.x, a2.x); a2.y = fmaf(wv, b2.y, a2.y);
                a2.z = fmaf(wv, b2.z, a2.z); a2.w = fmaf(wv, b2.w, a2.w);
                a3.x = fmaf(wv, b3.x, a3.x); a3.y = fmaf(wv, b3.y, a3.y);
                a3.z = fmaf(wv, b3.z, a3.z); a3.w = fmaf(wv, b3.w, a3.w);
            }
            float4* wrow = (float4*)&w4[g][d1][0];
            wrow[0] = a0; wrow[1] = a1; wrow[2] = a2; wrow[3] = a3;
        }
    }
    __syncthreads();
    {
        const int d1 = t >> 4;
        const float4* wr0 = (const float4*)&w4[0][d1][0];
        float4 wa = wr0[0], wb = wr0[1], wc = wr0[2], wd = wr0[3];
        float* outp = out + (size_t)base * 1024 + (t << 2);
        #pragma unroll
        for (int gg = 0; gg < 8; ++gg) {
            const float4* wrn = (const float4*)&w4[(gg + 1) & 7][d1][0];
            float4 na = wrn[0], nb = wrn[1], nc = wrn[2], nd = wrn[3];
            float4 acc = {0,0,0,0};
            STEP(wa.x,  0) STEP(wa.y,  1) STEP(wa.z,  2) STEP(wa.w,  3)
            STEP(wb.x,  4) STEP(wb.y,  5) STEP(wb.z,  6) STEP(wb.w,  7)
            STEP(wc.x,  8) STEP(wc.y,  9) STEP(wc.z, 10) STEP(wc.w, 11)
            STEP(wd.x, 12) STEP(wd.y, 13) STEP(wd.z, 14) STEP(wd.w, 15)
            if (base + gg < n_tokens)
                *(float4*)(outp + (size_t)gg * 1024) = acc;
            wa = na; wb = nb; wc = nc; wd = nd;
        }
    }
}

extern "C" void kernel_launch(void* const* d_in, const int* in_sizes, int n_in,
                              void* d_out, int out_size, void* d_ws, size_t ws_size,
                              hipStream_t stream) {
    const float* c0  = (const float*)d_in[0];
    const float* c1  = (const float*)d_in[1];
    const float* c2  = (const float*)d_in[2];
    const float* c3  = (const float*)d_in[3];
    const float* c4  = (const float*)d_in[4];
    const int*   idx = (const int*)d_in[5];
    float* out = (float*)d_out;

    const int n_tokens = in_sizes[5];                          // 16384
    const size_t ws_needed = (size_t)n_tokens * 16 * 16 * 4 + 256;  // ~16.8 MB

    if (ws_size >= ws_needed) {
        float* wsp = (float*)d_ws;
        const int gridA = (n_tokens + TA - 1) / TA;            // 1024
        const int gridB = (n_tokens + TB - 1) / TB;            // 4096
        tt_stage123<<<gridA, 256, 0, stream>>>(c0, c1, c2, c3, idx, wsp, n_tokens);
        tt_stage4<<<gridB, 256, 0, stream>>>(c4, wsp, out, n_tokens);
    } else {
        const int grid = (n_tokens + 7) / 8;
        tt_embed_fused<<<grid, 256, 0, stream>>>(c0, c1, c2, c3, c4, idx, out, n_tokens);
    }
}

// Round 9
// 31.258 us; speedup vs baseline: 1.5961x; 1.5961x over previous
//
#include <hip/hip_runtime.h>
#include <hip/hip_bf16.h>

// TT embedding: vocab 65536, dim 1024, rank 16.
// out[v,d] = sum_{r1..r4} c0[0,i0,r1] c1[r1,i1,r2] c2[r2,i2,r3] c3[r3,i3,r4] c4[r4,i4,0]
//   i0=v>>11, i1=(v>>6)&31, i2=(v>>1)&31, i3=(v&1)*16+(d>>6), i4=d&63
//
// R8 lesson: splits pay ws round-trip and still starve; best performers are
// the ones with the most INDEPENDENT waves (R1). R9: 16-lane group = one
// token END TO END. Zero barriers, zero cross-wave coupling, zero
// producer/consumer imbalance:
//   - stages 1-2: rank vectors passed lane-to-lane via __shfl(.., r, 16)
//     (exact data movement, same FMA order as R3/R7 which gave absmax 0.0)
//   - stage 3: lane r IS d1=r; accumulates its 16-wide w4 row in registers
//   - w4 transpose: within-wave LDS write/read, NO barrier (wave-local RAW,
//     proven by R5/R8 kernel A, absmax 0.0)
//   - stage 4: c4 cols r*4..r*4+3 in 64 VGPRs; 16 k-iters, 2-deep LDS read
//     pipeline, one nontemporal float4 store per iter (256B/instr per group)
// 1024 blocks x 256 thr; ~4 blocks/CU resident; every wave works start->end.

typedef float f32x4 __attribute__((ext_vector_type(4)));

#define STEP(WV, k)                              \
    acc.x = fmaf(WV, c4v[k].x, acc.x);           \
    acc.y = fmaf(WV, c4v[k].y, acc.y);           \
    acc.z = fmaf(WV, c4v[k].z, acc.z);           \
    acc.w = fmaf(WV, c4v[k].w, acc.w);

__global__ __launch_bounds__(256) void tt_embed_kernel(
    const float* __restrict__ c0,   // 32*16
    const float* __restrict__ c1,   // 16*32*16
    const float* __restrict__ c2,   // 16*32*16
    const float* __restrict__ c3,   // 16*32*16
    const float* __restrict__ c4,   // 16*64
    const int*   __restrict__ idx,  // n_tokens
    float*       __restrict__ out,  // n_tokens x 1024
    int n_tokens)
{
    const int t = threadIdx.x;
    const int g = t >> 4;            // token group within block (0..15)
    const int r = t & 15;            // lane within group
    const int token = blockIdx.x * 16 + g;
    const int v = (token < n_tokens) ? idx[token] : 0;

    __shared__ float w4[16][16][20];   // [g][d1][r4 pad 20]; rows 16B-aligned

    // ---- c4 column slice: lane covers output cols i4 = r*4 .. r*4+3
    float4 c4v[16];
    #pragma unroll
    for (int r4 = 0; r4 < 16; ++r4)
        c4v[r4] = *(const float4*)(c4 + (r4 << 6) + (r << 2));

    // ---- Stage 1: lane r owns w2[r] = sum_r1 c0[i0,r1] * c1[r1,i1,r]
    float w2r = 0.f;
    {
        const int i0 = (v >> 11) & 31;
        const int i1 = (v >> 6) & 31;
        #pragma unroll
        for (int r1 = 0; r1 < 16; ++r1)
            w2r = fmaf(c0[i0 * 16 + r1], c1[(r1 * 32 + i1) * 16 + r], w2r);
    }

    // ---- Stage 2: lane r owns w3[r] = sum_r2 w2[r2] * c2[r2,i2,r]
    float w3r = 0.f;
    {
        const int i2 = (v >> 1) & 31;
        #pragma unroll
        for (int r2 = 0; r2 < 16; ++r2)
            w3r = fmaf(__shfl(w2r, r2, 16), c2[(r2 * 32 + i2) * 16 + r], w3r);
    }

    // ---- Stage 3: lane r computes w4 row for d1 = r (16 accumulators)
    {
        const int i3 = ((v & 1) << 4) + r;
        float4 a0 = {0,0,0,0}, a1 = {0,0,0,0}, a2 = {0,0,0,0}, a3 = {0,0,0,0};
        #pragma unroll
        for (int r3 = 0; r3 < 16; ++r3) {
            const float wv = __shfl(w3r, r3, 16);
            const float4* row = (const float4*)(c3 + (r3 * 32 + i3) * 16);
            float4 b0 = row[0], b1 = row[1], b2 = row[2], b3 = row[3];
            a0.x = fmaf(wv, b0.x, a0.x); a0.y = fmaf(wv, b0.y, a0.y);
            a0.z = fmaf(wv, b0.z, a0.z); a0.w = fmaf(wv, b0.w, a0.w);
            a1.x = fmaf(wv, b1.x, a1.x); a1.y = fmaf(wv, b1.y, a1.y);
            a1.z = fmaf(wv, b1.z, a1.z); a1.w = fmaf(wv, b1.w, a1.w);
            a2.x = fmaf(wv, b2.x, a2.x); a2.y = fmaf(wv, b2.y, a2.y);
            a2.z = fmaf(wv, b2.z, a2.z); a2.w = fmaf(wv, b2.w, a2.w);
            a3.x = fmaf(wv, b3.x, a3.x); a3.y = fmaf(wv, b3.y, a3.y);
            a3.z = fmaf(wv, b3.z, a3.z); a3.w = fmaf(wv, b3.w, a3.w);
        }
        // within-wave transpose staging (no barrier needed: same wave)
        float4* wrow = (float4*)&w4[g][r][0];
        wrow[0] = a0; wrow[1] = a1; wrow[2] = a2; wrow[3] = a3;
    }

    // ---- Stage 4: out[token, k*64 + r*4 ..+3] = sum_r4 w4[g][k][r4]*c4v[r4]
    // 2-deep pipeline: k+1's row reads issue before k's 64-FMA block.
    {
        const float4* wr0 = (const float4*)&w4[g][0][0];
        float4 wa = wr0[0], wb = wr0[1], wc = wr0[2], wd = wr0[3];

        float* outp = out + (size_t)token * 1024 + (r << 2);

        #pragma unroll
        for (int k = 0; k < 16; ++k) {
            float4 na, nb, nc, nd;
            if (k + 1 < 16) {                 // compile-time after unroll
                const float4* wn = (const float4*)&w4[g][k + 1][0];
                na = wn[0]; nb = wn[1]; nc = wn[2]; nd = wn[3];
            }

            float4 acc = {0,0,0,0};
            STEP(wa.x,  0) STEP(wa.y,  1) STEP(wa.z,  2) STEP(wa.w,  3)
            STEP(wb.x,  4) STEP(wb.y,  5) STEP(wb.z,  6) STEP(wb.w,  7)
            STEP(wc.x,  8) STEP(wc.y,  9) STEP(wc.z, 10) STEP(wc.w, 11)
            STEP(wd.x, 12) STEP(wd.y, 13) STEP(wd.z, 14) STEP(wd.w, 15)

            if (token < n_tokens)
                __builtin_nontemporal_store(*(const f32x4*)&acc,
                                            (f32x4*)(outp + (k << 6)));

            wa = na; wb = nb; wc = nc; wd = nd;
        }
    }
}

extern "C" void kernel_launch(void* const* d_in, const int* in_sizes, int n_in,
                              void* d_out, int out_size, void* d_ws, size_t ws_size,
                              hipStream_t stream) {
    const float* c0  = (const float*)d_in[0];
    const float* c1  = (const float*)d_in[1];
    const float* c2  = (const float*)d_in[2];
    const float* c3  = (const float*)d_in[3];
    const float* c4  = (const float*)d_in[4];
    const int*   idx = (const int*)d_in[5];
    float* out = (float*)d_out;

    const int n_tokens = in_sizes[5];              // 8 * 2048 = 16384
    const int grid = (n_tokens + 15) / 16;         // 1024
    tt_embed_kernel<<<grid, 256, 0, stream>>>(c0, c1, c2, c3, c4, idx, out, n_tokens);
}